// Round 1
// baseline (2070.716 us; speedup 1.0000x reference)
//
#include <hip/hip_runtime.h>
#include <math.h>

#define EPSV 1e-5f

// ---------------------------------------------------------------------------
// conv3x3 (pad=1) + bias + BN (+ optional residual). COUT=64, co-tile=16.
// Block: 256 threads = 16x16 output pixels. Input staged in LDS in ci-chunks
// of 32 (18x18 halo tile). Weights read via uniform (scalar) loads.
// ---------------------------------------------------------------------------
template<int CIN, bool RES>
__global__ __launch_bounds__(256) void conv3x3_bn(
    const float* __restrict__ in,    // [B][CIN][128][128]
    const float* __restrict__ w,     // [64][CIN][3][3]
    const float* __restrict__ bias,  // [64]
    const float* __restrict__ bg, const float* __restrict__ bb,
    const float* __restrict__ bm, const float* __restrict__ bv,
    const float* __restrict__ resid, // [B][64][128][128] or null
    float* __restrict__ out)         // [B][64][128][128]
{
    __shared__ float lds[32 * 324];           // 32 ci x 18 x 18 = 41.5 KB
    const int tile = blockIdx.x;              // 0..63 (8x8 tiles of 16x16)
    const int co0  = blockIdx.y * 16;         // 0,16,32,48
    const int b    = blockIdx.z;
    const int y0 = (tile >> 3) * 16, x0 = (tile & 7) * 16;
    const int tid = threadIdx.x;
    const int ty = tid >> 4, tx = tid & 15;

    float acc[16];
#pragma unroll
    for (int i = 0; i < 16; ++i) acc[i] = 0.f;

    for (int cc = 0; cc < CIN; cc += 32) {
        __syncthreads();
        for (int f = tid; f < 32 * 324; f += 256) {
            int ci = f / 324;
            int r  = f - ci * 324;
            int yy = r / 18;
            int xx = r - yy * 18;
            int gy = y0 + yy - 1, gx = x0 + xx - 1;
            float val = 0.f;
            if (gy >= 0 && gy < 128 && gx >= 0 && gx < 128)
                val = in[((size_t)(b * CIN + cc + ci) << 14) + (gy << 7) + gx];
            lds[f] = val;
        }
        __syncthreads();
        for (int ci = 0; ci < 32; ++ci) {
            float v[9];
#pragma unroll
            for (int kh = 0; kh < 3; ++kh)
#pragma unroll
                for (int kw = 0; kw < 3; ++kw)
                    v[kh * 3 + kw] = lds[ci * 324 + (ty + kh) * 18 + (tx + kw)];
            const float* wp = w + ((size_t)co0 * CIN + (cc + ci)) * 9;
#pragma unroll
            for (int co = 0; co < 16; ++co) {
                const float* wc = wp + (size_t)co * CIN * 9;
                float a = acc[co];
                a += v[0] * wc[0]; a += v[1] * wc[1]; a += v[2] * wc[2];
                a += v[3] * wc[3]; a += v[4] * wc[4]; a += v[5] * wc[5];
                a += v[6] * wc[6]; a += v[7] * wc[7]; a += v[8] * wc[8];
                acc[co] = a;
            }
        }
    }

    const int gy = y0 + ty, gx = x0 + tx;
#pragma unroll
    for (int co = 0; co < 16; ++co) {
        int c = co0 + co;
        float s   = bg[c] * rsqrtf(bv[c] + EPSV);
        float val = (acc[co] + bias[c]) * s + (bb[c] - bm[c] * s);
        size_t oi = ((size_t)(b * 64 + c) << 14) + (gy << 7) + gx;
        if (RES) val += resid[oi];
        out[oi] = val;
    }
}

// ---------------------------------------------------------------------------
// gather q[b][n][c] = h[b][c][4*(n/32)][4*(n%32)]
// ---------------------------------------------------------------------------
__global__ __launch_bounds__(256) void gather_q(const float* __restrict__ h,
                                                float* __restrict__ q)
{
    int t = blockIdx.x * 256 + threadIdx.x;   // < 16*1024*64
    int c = t & 63;
    int n = (t >> 6) & 1023;
    int b = t >> 16;
    q[t] = h[((size_t)(b * 64 + c) << 14) + ((n >> 5) << 9) + ((n & 31) << 2)];
}

// ---------------------------------------------------------------------------
// S[b][n][m] = 0.125 * sum_c q[b][n][c]*q[b][m][c].  64x64 tile, K=64.
// ---------------------------------------------------------------------------
__global__ __launch_bounds__(256) void qk_gemm(const float* __restrict__ q,
                                               float* __restrict__ S)
{
    __shared__ float a_lds[64 * 68];  // [k][n]
    __shared__ float b_lds[64 * 68];  // [k][m]
    const int m0 = blockIdx.x * 64;
    const int n0 = blockIdx.y * 64;
    const int b  = blockIdx.z;
    const int tid = threadIdx.x;
    const float* qb = q + ((size_t)b << 16);

    for (int f = tid; f < 4096; f += 256) {
        int row = f >> 6, k = f & 63;
        a_lds[k * 68 + row] = qb[(size_t)(n0 + row) * 64 + k];
        b_lds[k * 68 + row] = qb[(size_t)(m0 + row) * 64 + k];
    }
    __syncthreads();

    const int tx = tid & 15, ty = tid >> 4;
    float acc[4][4] = {};
    for (int k = 0; k < 64; ++k) {
        float4 a4 = *(const float4*)&a_lds[k * 68 + ty * 4];
        float4 b4 = *(const float4*)&b_lds[k * 68 + tx * 4];
        float av[4] = {a4.x, a4.y, a4.z, a4.w};
        float bw[4] = {b4.x, b4.y, b4.z, b4.w};
#pragma unroll
        for (int i = 0; i < 4; ++i)
#pragma unroll
            for (int j = 0; j < 4; ++j) acc[i][j] += av[i] * bw[j];
    }

#pragma unroll
    for (int i = 0; i < 4; ++i) {
        int n = n0 + ty * 4 + i;
        float4 st = make_float4(acc[i][0] * 0.125f, acc[i][1] * 0.125f,
                                acc[i][2] * 0.125f, acc[i][3] * 0.125f);
        *(float4*)&S[((((size_t)b << 10) + n) << 10) + m0 + tx * 4] = st;
    }
}

// ---------------------------------------------------------------------------
// in-place row softmax over 1024 elements. 1 block (256 thr) per row.
// ---------------------------------------------------------------------------
__global__ __launch_bounds__(256) void softmax_rows(float* __restrict__ S)
{
    __shared__ float red[8];
    const size_t row = blockIdx.x;
    float4* p = (float4*)(S + (row << 10));
    const int tid = threadIdx.x;
    float4 v = p[tid];

    float m = fmaxf(fmaxf(v.x, v.y), fmaxf(v.z, v.w));
#pragma unroll
    for (int off = 32; off; off >>= 1) m = fmaxf(m, __shfl_xor(m, off));
    if ((tid & 63) == 0) red[tid >> 6] = m;
    __syncthreads();
    m = fmaxf(fmaxf(red[0], red[1]), fmaxf(red[2], red[3]));

    v.x = __expf(v.x - m); v.y = __expf(v.y - m);
    v.z = __expf(v.z - m); v.w = __expf(v.w - m);
    float s = v.x + v.y + v.z + v.w;
#pragma unroll
    for (int off = 32; off; off >>= 1) s += __shfl_xor(s, off);
    if ((tid & 63) == 0) red[4 + (tid >> 6)] = s;
    __syncthreads();
    float inv = 1.f / (red[4] + red[5] + red[6] + red[7]);

    v.x *= inv; v.y *= inv; v.z *= inv; v.w *= inv;
    p[tid] = v;
}

// ---------------------------------------------------------------------------
// o_img[b][c][r][col] = sum_m att[b][n][m]*q[b][m][c], n=r*32+col.
// Block tile: 64 n x 64 c, K-loop over m in 64-chunks.
// ---------------------------------------------------------------------------
__global__ __launch_bounds__(256) void av_gemm(const float* __restrict__ att,
                                               const float* __restrict__ q,
                                               float* __restrict__ o)
{
    __shared__ float a_lds[64 * 68];  // [m][n]
    __shared__ float b_lds[64 * 68];  // [m][c]
    const int n0 = blockIdx.x * 64;
    const int b  = blockIdx.y;
    const int tid = threadIdx.x;
    const int tx = tid & 15, ty = tid >> 4;
    const float* ab = att + ((size_t)b << 20);
    const float* qb = q + ((size_t)b << 16);

    float acc[4][4] = {};
    for (int mt = 0; mt < 1024; mt += 64) {
        __syncthreads();
        for (int f = tid; f < 4096; f += 256) {
            int row = f >> 6, k = f & 63;
            a_lds[k * 68 + row] = ab[((size_t)(n0 + row) << 10) + mt + k];
            b_lds[row * 68 + k] = qb[(size_t)(mt + row) * 64 + k];
        }
        __syncthreads();
        for (int k = 0; k < 64; ++k) {
            float4 a4 = *(const float4*)&a_lds[k * 68 + ty * 4];
            float4 b4 = *(const float4*)&b_lds[k * 68 + tx * 4];
            float av[4] = {a4.x, a4.y, a4.z, a4.w};
            float bw[4] = {b4.x, b4.y, b4.z, b4.w};
#pragma unroll
            for (int i = 0; i < 4; ++i)
#pragma unroll
                for (int j = 0; j < 4; ++j) acc[i][j] += av[i] * bw[j];
        }
    }

#pragma unroll
    for (int i = 0; i < 4; ++i)
#pragma unroll
        for (int j = 0; j < 4; ++j) {
            int n = n0 + ty * 4 + i;
            int c = tx * 4 + j;
            o[(((size_t)(b * 64 + c)) << 10) + n] = acc[i][j];
        }
}

// ---------------------------------------------------------------------------
// conv1x1 (128->128) + bias + BN + exact GELU.
// Block: 256 threads = 16x16 pixels; input (h ++ upsampled o) staged in LDS
// in two 64-channel chunks; 4 co-tiles of 32.
// ---------------------------------------------------------------------------
__global__ __launch_bounds__(256) void conv1x1_bn_gelu(
    const float* __restrict__ h,   // [B][64][128][128]
    const float* __restrict__ o,   // [B][64][32][32]
    const float* __restrict__ w,   // [128][128]
    const float* __restrict__ bias,
    const float* __restrict__ bg, const float* __restrict__ bb,
    const float* __restrict__ bm, const float* __restrict__ bv,
    float* __restrict__ g)         // [B][128][128][128]
{
    __shared__ float lds[64 * 256];          // 64 KB
    const int tile = blockIdx.x;             // 0..63
    const int b = blockIdx.y;
    const int y0 = (tile >> 3) * 16, x0 = (tile & 7) * 16;
    const int tid = threadIdx.x;
    const int gy = y0 + (tid >> 4), gx = x0 + (tid & 15);

    for (int cot = 0; cot < 4; ++cot) {
        float acc[32];
#pragma unroll
        for (int i = 0; i < 32; ++i) acc[i] = 0.f;

        for (int ch = 0; ch < 2; ++ch) {
            __syncthreads();
            for (int f = tid; f < 64 * 256; f += 256) {
                int ci = f >> 8;
                int p  = f & 255;
                int yy = y0 + (p >> 4), xx = x0 + (p & 15);
                float val;
                if (ch == 0)
                    val = h[((size_t)(b * 64 + ci) << 14) + (yy << 7) + xx];
                else
                    val = o[((size_t)(b * 64 + ci) << 10) + ((yy >> 2) << 5) + (xx >> 2)];
                lds[f] = val;
            }
            __syncthreads();
            for (int ci = 0; ci < 64; ++ci) {
                float v = lds[ci * 256 + tid];
                const float* wp = w + (size_t)(cot * 32) * 128 + ch * 64 + ci;
#pragma unroll
                for (int co = 0; co < 32; ++co)
                    acc[co] += v * wp[(size_t)co * 128];
            }
        }

#pragma unroll
        for (int co = 0; co < 32; ++co) {
            int c = cot * 32 + co;
            float s   = bg[c] * rsqrtf(bv[c] + EPSV);
            float val = (acc[co] + bias[c]) * s + (bb[c] - bm[c] * s);
            float ge  = 0.5f * val * (1.f + erff(val * 0.70710678118654752f));
            g[((size_t)(b * 128 + c) << 14) + (gy << 7) + gx] = ge;
        }
    }
}

// ---------------------------------------------------------------------------
extern "C" void kernel_launch(void* const* d_in, const int* in_sizes, int n_in,
                              void* d_out, int out_size, void* d_ws, size_t ws_size,
                              hipStream_t stream)
{
    const float* x     = (const float*)d_in[0];
    const float* fc1_w = (const float*)d_in[1];
    const float* fc1_b = (const float*)d_in[2];
    const float* bn1_g = (const float*)d_in[3];
    const float* bn1_b = (const float*)d_in[4];
    const float* bn1_m = (const float*)d_in[5];
    const float* bn1_v = (const float*)d_in[6];
    const float* gc_w  = (const float*)d_in[7];
    const float* gc_b  = (const float*)d_in[8];
    const float* bng_g = (const float*)d_in[9];
    const float* bng_b = (const float*)d_in[10];
    const float* bng_m = (const float*)d_in[11];
    const float* bng_v = (const float*)d_in[12];
    const float* fc2_w = (const float*)d_in[13];
    const float* fc2_b = (const float*)d_in[14];
    const float* bn2_g = (const float*)d_in[15];
    const float* bn2_b = (const float*)d_in[16];
    const float* bn2_m = (const float*)d_in[17];
    const float* bn2_v = (const float*)d_in[18];

    float* ws = (float*)d_ws;
    float* h  = ws;                      // 16*64*128*128   = 16,777,216 f
    float* q  = ws + 16777216;           // 16*1024*64      =  1,048,576 f
    float* o  = q + 1048576;             // 16*64*32*32     =  1,048,576 f
    float* g  = o + 1048576;             // 16*128*128*128  = 33,554,432 f
    float* S  = g;                       // 16*1024*1024 aliases g (S dies first)

    conv3x3_bn<64, false><<<dim3(64, 4, 16), 256, 0, stream>>>(
        x, fc1_w, fc1_b, bn1_g, bn1_b, bn1_m, bn1_v, nullptr, h);

    gather_q<<<4096, 256, 0, stream>>>(h, q);

    qk_gemm<<<dim3(16, 16, 16), 256, 0, stream>>>(q, S);

    softmax_rows<<<16384, 256, 0, stream>>>(S);

    av_gemm<<<dim3(16, 16), 256, 0, stream>>>(S, q, o);

    conv1x1_bn_gelu<<<dim3(64, 16), 256, 0, stream>>>(
        h, o, gc_w, gc_b, bng_g, bng_b, bng_m, bng_v, g);

    conv3x3_bn<128, true><<<dim3(64, 4, 16), 256, 0, stream>>>(
        g, fc2_w, fc2_b, bn2_g, bn2_b, bn2_m, bn2_v, x, (float*)d_out);
}

// Round 2
// 324.051 us; speedup vs baseline: 6.3901x; 6.3901x over previous
//
#include <hip/hip_runtime.h>
#include <math.h>

#define EPSV 1e-5f

typedef __bf16 bf16;
using bf16x8 = __attribute__((ext_vector_type(8))) __bf16;
using bf16x4 = __attribute__((ext_vector_type(4))) __bf16;
using bf16x2 = __attribute__((ext_vector_type(2))) __bf16;
using f32x4  = __attribute__((ext_vector_type(4))) float;

static __device__ __forceinline__ f32x4 mfma16(bf16x8 a, bf16x8 b, f32x4 c) {
    return __builtin_amdgcn_mfma_f32_16x16x32_bf16(a, b, c, 0, 0, 0);
}
static __device__ __forceinline__ f32x4 zero4() {
    f32x4 z = {0.f, 0.f, 0.f, 0.f};
    return z;
}
static __device__ __forceinline__ bf16x8 zero8() {
    bf16x8 z = {(bf16)0.f,(bf16)0.f,(bf16)0.f,(bf16)0.f,
                (bf16)0.f,(bf16)0.f,(bf16)0.f,(bf16)0.f};
    return z;
}

// ---------------------------------------------------------------------------
// x fp32 NCHW [16][64][128][128] -> bf16 NHWC [16][128][128][64]
// block: one (b, y, x-half); LDS transpose tile 64x x 64c.
// ---------------------------------------------------------------------------
__global__ __launch_bounds__(256) void cvt_x_nhwc(const float* __restrict__ x,
                                                  bf16* __restrict__ xb)
{
    __shared__ float t_lds[64 * 68];
    const int bx = blockIdx.x;          // 0..255: y = bx>>1, half = bx&1
    const int b  = blockIdx.y;
    const int y  = bx >> 1, x0 = (bx & 1) * 64;
    const int tid = threadIdx.x;

    for (int f = tid; f < 64 * 16; f += 256) {
        int c = f >> 4, xu = f & 15;
        float4 v = *(const float4*)&x[((size_t)(b * 64 + c) << 14) + (y << 7) + x0 + xu * 4];
        t_lds[(xu * 4 + 0) * 68 + c] = v.x;
        t_lds[(xu * 4 + 1) * 68 + c] = v.y;
        t_lds[(xu * 4 + 2) * 68 + c] = v.z;
        t_lds[(xu * 4 + 3) * 68 + c] = v.w;
    }
    __syncthreads();
    for (int f = tid; f < 64 * 8; f += 256) {
        int xx = f >> 3, cu = f & 7;
        const float* p = &t_lds[xx * 68 + cu * 8];
        bf16x8 v;
#pragma unroll
        for (int j = 0; j < 8; ++j) v[j] = (bf16)p[j];
        *(bf16x8*)&xb[((size_t)((b * 128 + y) * 128) + x0 + xx) * 64 + cu * 8] = v;
    }
}

// ---------------------------------------------------------------------------
// conv3x3 via MFMA implicit GEMM. Input bf16 NHWC [B][128][128][CIN].
// COUT=64. Block = 256 thr = 4 waves; pixel tile 64x(x) by 4(y); wave = row.
// 9 shifts = 3 kg-groups (kernel rows) x 3 kw. LDS: input halo [6][66][40],
// weights [3][64][40] restaged per (ci-chunk, kg).
// OUTMODE 0: out bf16 NHWC + BN.  OUTMODE 1: out fp32 NCHW + BN + residual.
// ---------------------------------------------------------------------------
template<int CIN, int OUTMODE>
__global__ __launch_bounds__(256) void conv3x3_mfma(
    const bf16* __restrict__ in, const float* __restrict__ w,
    const float* __restrict__ bias,
    const float* __restrict__ bg, const float* __restrict__ bb,
    const float* __restrict__ bm, const float* __restrict__ bv,
    const float* __restrict__ resid, void* __restrict__ outp)
{
    constexpr int CIp = 40;
    __shared__ bf16 in_lds[6 * 66 * CIp];    // 31680 B
    __shared__ bf16 w_lds[3 * 64 * CIp];     // 15360 B

    const int tile = blockIdx.x;             // 0..63
    const int b    = blockIdx.y;
    const int x0 = (tile & 1) * 64;
    const int y0 = (tile >> 1) * 4;
    const int tid  = threadIdx.x;
    const int wid  = tid >> 6;
    const int lane = tid & 63;
    const int lix  = lane & 15, lg = lane >> 4;

    f32x4 acc[4][4];
#pragma unroll
    for (int i = 0; i < 4; ++i)
#pragma unroll
        for (int j = 0; j < 4; ++j) acc[i][j] = zero4();

    for (int cc = 0; cc < CIN; cc += 32) {
        __syncthreads();
        // stage input halo tile 6 x 66 x 32 (16B units)
        for (int f = tid; f < 6 * 66 * 4; f += 256) {
            int u   = f & 3;
            int pix = f >> 2;
            int iy  = pix / 66;
            int ix  = pix - iy * 66;
            int gy = y0 + iy - 1, gx = x0 + ix - 1;
            bf16x8 v = zero8();
            if (gy >= 0 && gy < 128 && gx >= 0 && gx < 128)
                v = *(const bf16x8*)&in[((size_t)((b * 128 + gy) * 128 + gx)) * CIN + cc + u * 8];
            *(bf16x8*)&in_lds[(iy * 66 + ix) * CIp + u * 8] = v;
        }
        for (int kg = 0; kg < 3; ++kg) {
            __syncthreads();
            // stage weights for kernel-row kg: w_lds[t][cout][ci], t=kw
            for (int f = tid; f < 64 * 16; f += 256) {
                int cout = f >> 4, ci2 = f & 15;
                const float* wp  = w + ((size_t)cout * CIN + cc + 2 * ci2) * 9 + kg * 3;
                const float* wp2 = wp + 9;
#pragma unroll
                for (int t = 0; t < 3; ++t) {
                    bf16x2 wv = {(bf16)wp[t], (bf16)wp2[t]};
                    *(bf16x2*)&w_lds[(t * 64 + cout) * CIp + 2 * ci2] = wv;
                }
            }
            __syncthreads();
#pragma unroll
            for (int t = 0; t < 3; ++t) {
                bf16x8 af[4];
#pragma unroll
                for (int mi = 0; mi < 4; ++mi)
                    af[mi] = *(const bf16x8*)&w_lds[(t * 64 + mi * 16 + lix) * CIp + lg * 8];
                const int rowb = (wid + kg) * 66 + lix + t;
#pragma unroll
                for (int nj = 0; nj < 4; ++nj) {
                    bf16x8 bfr = *(const bf16x8*)&in_lds[(rowb + nj * 16) * CIp + lg * 8];
#pragma unroll
                    for (int mi = 0; mi < 4; ++mi)
                        acc[mi][nj] = mfma16(af[mi], bfr, acc[mi][nj]);
                }
            }
        }
    }

    const int gy = y0 + wid;
#pragma unroll
    for (int mi = 0; mi < 4; ++mi) {
        float A[4], Bc[4];
#pragma unroll
        for (int r = 0; r < 4; ++r) {
            int c = mi * 16 + lg * 4 + r;
            float s = bg[c] * rsqrtf(bv[c] + EPSV);
            A[r]  = s;
            Bc[r] = bias[c] * s + bb[c] - bm[c] * s;
        }
        if (OUTMODE == 0) {
            bf16* out = (bf16*)outp;
#pragma unroll
            for (int nj = 0; nj < 4; ++nj) {
                int px = x0 + nj * 16 + lix;
                bf16x4 vv;
#pragma unroll
                for (int r = 0; r < 4; ++r)
                    vv[r] = (bf16)(acc[mi][nj][r] * A[r] + Bc[r]);
                *(bf16x4*)&out[((size_t)((b * 128 + gy) * 128) + px) * 64 + mi * 16 + lg * 4] = vv;
            }
        } else {
            float* out = (float*)outp;
#pragma unroll
            for (int nj = 0; nj < 4; ++nj) {
                int px = x0 + nj * 16 + lix;
#pragma unroll
                for (int r = 0; r < 4; ++r) {
                    int c = mi * 16 + lg * 4 + r;
                    size_t oi = ((size_t)(b * 64 + c) << 14) + (gy << 7) + px;
                    out[oi] = acc[mi][nj][r] * A[r] + Bc[r] + resid[oi];
                }
            }
        }
    }
}

// ---------------------------------------------------------------------------
// q[b][n][c] = h[b][4*(n/32)][4*(n%32)][c]   (bf16, 16B units)
// ---------------------------------------------------------------------------
__global__ __launch_bounds__(256) void gather_q(const bf16* __restrict__ h,
                                                bf16* __restrict__ q)
{
    int t = blockIdx.x * 256 + threadIdx.x;   // < 16*1024*8
    int cu = t & 7, n = (t >> 3) & 1023, b = t >> 13;
    int y = (n >> 5) << 2, x = (n & 31) << 2;
    bf16x8 v = *(const bf16x8*)&h[((size_t)((b * 128 + y) * 128 + x)) * 64 + cu * 8];
    *(bf16x8*)&q[((size_t)(b * 1024 + n)) * 64 + cu * 8] = v;
}

// ---------------------------------------------------------------------------
// S[b][n][m] = 0.125 * sum_c q[n][c] q[m][c].  Block 128n x 128m, K=64.
// ---------------------------------------------------------------------------
__global__ __launch_bounds__(256) void qk_mfma(const bf16* __restrict__ q,
                                               float* __restrict__ S)
{
    __shared__ bf16 qa[128 * 72];
    __shared__ bf16 qb[128 * 72];
    const int m0 = blockIdx.x * 128, n0 = blockIdx.y * 128, b = blockIdx.z;
    const int tid = threadIdx.x;
    const int wid = tid >> 6, lane = tid & 63;
    const int lix = lane & 15, lg = lane >> 4;
    const int wm = wid >> 1, wn = wid & 1;

    for (int f = tid; f < 128 * 8; f += 256) {
        int row = f >> 3, cu = f & 7;
        *(bf16x8*)&qa[row * 72 + cu * 8] =
            *(const bf16x8*)&q[((size_t)(b * 1024 + n0 + row)) * 64 + cu * 8];
        *(bf16x8*)&qb[row * 72 + cu * 8] =
            *(const bf16x8*)&q[((size_t)(b * 1024 + m0 + row)) * 64 + cu * 8];
    }
    __syncthreads();

    f32x4 acc[4][4];
#pragma unroll
    for (int i = 0; i < 4; ++i)
#pragma unroll
        for (int j = 0; j < 4; ++j) acc[i][j] = zero4();

#pragma unroll
    for (int ks = 0; ks < 2; ++ks) {
        bf16x8 af[4], bfv[4];
#pragma unroll
        for (int mi = 0; mi < 4; ++mi)
            af[mi] = *(const bf16x8*)&qa[(wm * 64 + mi * 16 + lix) * 72 + ks * 32 + lg * 8];
#pragma unroll
        for (int nj = 0; nj < 4; ++nj)
            bfv[nj] = *(const bf16x8*)&qb[(wn * 64 + nj * 16 + lix) * 72 + ks * 32 + lg * 8];
#pragma unroll
        for (int mi = 0; mi < 4; ++mi)
#pragma unroll
            for (int nj = 0; nj < 4; ++nj)
                acc[mi][nj] = mfma16(af[mi], bfv[nj], acc[mi][nj]);
    }

#pragma unroll
    for (int mi = 0; mi < 4; ++mi)
#pragma unroll
        for (int nj = 0; nj < 4; ++nj)
#pragma unroll
            for (int r = 0; r < 4; ++r) {
                int n = n0 + wm * 64 + mi * 16 + lg * 4 + r;
                int m = m0 + wn * 64 + nj * 16 + lix;
                S[((size_t)(b * 1024 + n) << 10) + m] = acc[mi][nj][r] * 0.125f;
            }
}

// ---------------------------------------------------------------------------
// in-place row softmax over 1024 f32. 1 block per row.
// ---------------------------------------------------------------------------
__global__ __launch_bounds__(256) void softmax_rows(float* __restrict__ S)
{
    __shared__ float red[8];
    const size_t row = blockIdx.x;
    float4* p = (float4*)(S + (row << 10));
    const int tid = threadIdx.x;
    float4 v = p[tid];

    float m = fmaxf(fmaxf(v.x, v.y), fmaxf(v.z, v.w));
#pragma unroll
    for (int off = 32; off; off >>= 1) m = fmaxf(m, __shfl_xor(m, off));
    if ((tid & 63) == 0) red[tid >> 6] = m;
    __syncthreads();
    m = fmaxf(fmaxf(red[0], red[1]), fmaxf(red[2], red[3]));

    v.x = __expf(v.x - m); v.y = __expf(v.y - m);
    v.z = __expf(v.z - m); v.w = __expf(v.w - m);
    float s = v.x + v.y + v.z + v.w;
#pragma unroll
    for (int off = 32; off; off >>= 1) s += __shfl_xor(s, off);
    if ((tid & 63) == 0) red[4 + (tid >> 6)] = s;
    __syncthreads();
    float inv = 1.f / (red[4] + red[5] + red[6] + red[7]);

    v.x *= inv; v.y *= inv; v.z *= inv; v.w *= inv;
    p[tid] = v;
}

// ---------------------------------------------------------------------------
// o[b][n][c] = sum_m P[n][m] q[m][c]; P = softmaxed S (fp32, cvt on stage).
// Block 64n x 64c, K staged in 64-chunks; q transposed into LDS [c][m].
// ---------------------------------------------------------------------------
__global__ __launch_bounds__(256) void av_mfma(const float* __restrict__ S,
                                               const bf16* __restrict__ q,
                                               bf16* __restrict__ ov)
{
    __shared__ bf16 P_lds[64 * 72];
    __shared__ bf16 qT_lds[64 * 72];
    const int n0 = blockIdx.x * 64, b = blockIdx.y;
    const int tid = threadIdx.x;
    const int wid = tid >> 6, lane = tid & 63;
    const int lix = lane & 15, lg = lane >> 4;
    const int wm = wid >> 1, wn = wid & 1;

    f32x4 acc[2][2];
#pragma unroll
    for (int i = 0; i < 2; ++i)
#pragma unroll
        for (int j = 0; j < 2; ++j) acc[i][j] = zero4();

    for (int mt = 0; mt < 1024; mt += 64) {
        __syncthreads();
        for (int f = tid; f < 64 * 16; f += 256) {
            int n = f >> 4, mu = f & 15;
            float4 v = *(const float4*)&S[((size_t)(b * 1024 + n0 + n) << 10) + mt + mu * 4];
            bf16x4 pv = {(bf16)v.x, (bf16)v.y, (bf16)v.z, (bf16)v.w};
            *(bf16x4*)&P_lds[n * 72 + mu * 4] = pv;
        }
        for (int f = tid; f < 64 * 8; f += 256) {
            int m = f >> 3, cu = f & 7;
            bf16x8 v = *(const bf16x8*)&q[((size_t)(b * 1024 + mt + m)) * 64 + cu * 8];
#pragma unroll
            for (int j = 0; j < 8; ++j) qT_lds[(cu * 8 + j) * 72 + m] = v[j];
        }
        __syncthreads();
#pragma unroll
        for (int ks = 0; ks < 2; ++ks) {
            bf16x8 af[2], bfv[2];
#pragma unroll
            for (int mi = 0; mi < 2; ++mi)
                af[mi] = *(const bf16x8*)&P_lds[(wm * 32 + mi * 16 + lix) * 72 + ks * 32 + lg * 8];
#pragma unroll
            for (int nj = 0; nj < 2; ++nj)
                bfv[nj] = *(const bf16x8*)&qT_lds[(wn * 32 + nj * 16 + lix) * 72 + ks * 32 + lg * 8];
#pragma unroll
            for (int mi = 0; mi < 2; ++mi)
#pragma unroll
                for (int nj = 0; nj < 2; ++nj)
                    acc[mi][nj] = mfma16(af[mi], bfv[nj], acc[mi][nj]);
        }
    }

#pragma unroll
    for (int mi = 0; mi < 2; ++mi)
#pragma unroll
        for (int nj = 0; nj < 2; ++nj)
#pragma unroll
            for (int r = 0; r < 4; ++r) {
                int n = n0 + wm * 32 + mi * 16 + lg * 4 + r;
                int c = wn * 32 + nj * 16 + lix;
                ov[((size_t)(b * 1024 + n)) * 64 + c] = (bf16)acc[mi][nj][r];
            }
}

// ---------------------------------------------------------------------------
// conv1x1 (128->128) + BN + GELU via MFMA. Block = one image row (128 px),
// K = 128 = [h(64) ++ o-upsampled(64)]. Output g bf16 NHWC.
// ---------------------------------------------------------------------------
__global__ __launch_bounds__(256) void conv1x1_mfma(
    const bf16* __restrict__ h, const bf16* __restrict__ ov,
    const float* __restrict__ w, const float* __restrict__ bias,
    const float* __restrict__ bg, const float* __restrict__ bb,
    const float* __restrict__ bm, const float* __restrict__ bv,
    bf16* __restrict__ g)
{
    __shared__ bf16 in1[128 * 136];
    __shared__ bf16 w1[128 * 136];
    const int y = blockIdx.x, b = blockIdx.y;
    const int tid = threadIdx.x;
    const int wid = tid >> 6, lane = tid & 63;
    const int lix = lane & 15, lg = lane >> 4;
    const int wm = wid >> 1, wn = wid & 1;

    for (int f = tid; f < 128 * 16; f += 256) {
        int px = f >> 4, cu = f & 15;
        bf16x8 v;
        if (cu < 8) {
            v = *(const bf16x8*)&h[((size_t)((b * 128 + y) * 128 + px)) * 64 + cu * 8];
        } else {
            int n = ((y >> 2) << 5) + (px >> 2);
            v = *(const bf16x8*)&ov[((size_t)(b * 1024 + n)) * 64 + (cu - 8) * 8];
        }
        *(bf16x8*)&in1[px * 136 + cu * 8] = v;
    }
    for (int f = tid; f < 128 * 64; f += 256) {
        int co = f >> 6, cp = f & 63;
        float2 v = *(const float2*)&w[co * 128 + cp * 2];
        bf16x2 wv = {(bf16)v.x, (bf16)v.y};
        *(bf16x2*)&w1[co * 136 + cp * 2] = wv;
    }
    __syncthreads();

    f32x4 acc[4][4];
#pragma unroll
    for (int i = 0; i < 4; ++i)
#pragma unroll
        for (int j = 0; j < 4; ++j) acc[i][j] = zero4();

#pragma unroll
    for (int ks = 0; ks < 4; ++ks) {
        bf16x8 af[4], bfv[4];
#pragma unroll
        for (int mi = 0; mi < 4; ++mi)
            af[mi] = *(const bf16x8*)&w1[(wm * 64 + mi * 16 + lix) * 136 + ks * 32 + lg * 8];
#pragma unroll
        for (int nj = 0; nj < 4; ++nj)
            bfv[nj] = *(const bf16x8*)&in1[(wn * 64 + nj * 16 + lix) * 136 + ks * 32 + lg * 8];
#pragma unroll
        for (int mi = 0; mi < 4; ++mi)
#pragma unroll
            for (int nj = 0; nj < 4; ++nj)
                acc[mi][nj] = mfma16(af[mi], bfv[nj], acc[mi][nj]);
    }

#pragma unroll
    for (int mi = 0; mi < 4; ++mi) {
        float A[4], Bc[4];
#pragma unroll
        for (int r = 0; r < 4; ++r) {
            int c = wm * 64 + mi * 16 + lg * 4 + r;
            float s = bg[c] * rsqrtf(bv[c] + EPSV);
            A[r]  = s;
            Bc[r] = bias[c] * s + bb[c] - bm[c] * s;
        }
#pragma unroll
        for (int nj = 0; nj < 4; ++nj) {
            int px = wn * 64 + nj * 16 + lix;
            bf16x4 vv;
#pragma unroll
            for (int r = 0; r < 4; ++r) {
                float val = acc[mi][nj][r] * A[r] + Bc[r];
                float ge  = 0.5f * val * (1.f + erff(val * 0.70710678f));
                vv[r] = (bf16)ge;
            }
            *(bf16x4*)&g[((size_t)((b * 128 + y) * 128 + px)) * 128 + wm * 64 + mi * 16 + lg * 4] = vv;
        }
    }
}

// ---------------------------------------------------------------------------
extern "C" void kernel_launch(void* const* d_in, const int* in_sizes, int n_in,
                              void* d_out, int out_size, void* d_ws, size_t ws_size,
                              hipStream_t stream)
{
    const float* x     = (const float*)d_in[0];
    const float* fc1_w = (const float*)d_in[1];
    const float* fc1_b = (const float*)d_in[2];
    const float* bn1_g = (const float*)d_in[3];
    const float* bn1_b = (const float*)d_in[4];
    const float* bn1_m = (const float*)d_in[5];
    const float* bn1_v = (const float*)d_in[6];
    const float* gc_w  = (const float*)d_in[7];
    const float* gc_b  = (const float*)d_in[8];
    const float* bng_g = (const float*)d_in[9];
    const float* bng_b = (const float*)d_in[10];
    const float* bng_m = (const float*)d_in[11];
    const float* bng_v = (const float*)d_in[12];
    const float* fc2_w = (const float*)d_in[13];
    const float* fc2_b = (const float*)d_in[14];
    const float* bn2_g = (const float*)d_in[15];
    const float* bn2_b = (const float*)d_in[16];
    const float* bn2_m = (const float*)d_in[17];
    const float* bn2_v = (const float*)d_in[18];

    char* wsb = (char*)d_ws;
    bf16* x_bf = (bf16*)wsb;                            // 33,554,432 B
    bf16* h    = (bf16*)(wsb + 33554432);               // 33,554,432 B
    bf16* g    = (bf16*)(wsb + 67108864);               // 67,108,864 B
    bf16* q    = (bf16*)(wsb + 134217728);              //  2,097,152 B
    bf16* o    = (bf16*)(wsb + 136314880);              //  2,097,152 B
    float* S   = (float*)(wsb + 138412032);             // 67,108,864 B (end ~205.5MB)

    cvt_x_nhwc<<<dim3(256, 16), 256, 0, stream>>>(x, x_bf);

    conv3x3_mfma<64, 0><<<dim3(64, 16), 256, 0, stream>>>(
        x_bf, fc1_w, fc1_b, bn1_g, bn1_b, bn1_m, bn1_v, nullptr, h);

    gather_q<<<512, 256, 0, stream>>>(h, q);

    qk_mfma<<<dim3(8, 8, 16), 256, 0, stream>>>(q, S);

    softmax_rows<<<16384, 256, 0, stream>>>(S);

    av_mfma<<<dim3(16, 16), 256, 0, stream>>>(S, q, o);

    conv1x1_mfma<<<dim3(128, 16), 256, 0, stream>>>(
        h, o, gc_w, gc_b, bng_g, bng_b, bng_m, bng_v, g);

    conv3x3_mfma<128, 1><<<dim3(64, 16), 256, 0, stream>>>(
        g, fc2_w, fc2_b, bn2_g, bn2_b, bn2_m, bn2_v, x, (float*)d_out);
}

// Round 3
// 207.325 us; speedup vs baseline: 9.9878x; 1.5630x over previous
//
#include <hip/hip_runtime.h>
#include <math.h>

#define EPSV 1e-5f

typedef __bf16 bf16;
using bf16x8 = __attribute__((ext_vector_type(8))) __bf16;
using bf16x4 = __attribute__((ext_vector_type(4))) __bf16;
using bf16x2 = __attribute__((ext_vector_type(2))) __bf16;
using f32x4  = __attribute__((ext_vector_type(4))) float;

static __device__ __forceinline__ f32x4 mfma16(bf16x8 a, bf16x8 b, f32x4 c) {
    return __builtin_amdgcn_mfma_f32_16x16x32_bf16(a, b, c, 0, 0, 0);
}
static __device__ __forceinline__ f32x4 zero4() {
    f32x4 z = {0.f, 0.f, 0.f, 0.f};
    return z;
}
static __device__ __forceinline__ bf16x8 zero8() {
    bf16x8 z = {(bf16)0.f,(bf16)0.f,(bf16)0.f,(bf16)0.f,
                (bf16)0.f,(bf16)0.f,(bf16)0.f,(bf16)0.f};
    return z;
}

// ---------------------------------------------------------------------------
// Weight prep: conv3x3 fp32 [cout][CIN][3][3] -> bf16 fragment-major
// wt[(((kgt*(CIN/32)+cci)*4+lg)*64 + cout)*8 + j], ci = cci*32+lg*8+j.
// ---------------------------------------------------------------------------
template<int CIN>
__global__ __launch_bounds__(256) void prep_conv_w(const float* __restrict__ w,
                                                   bf16* __restrict__ wt)
{
    int t = blockIdx.x * 256 + threadIdx.x;      // cout*CIN + ci
    if (t >= 64 * CIN) return;
    int cout = t / CIN, ci = t - cout * CIN;
    int cci = ci >> 5, lg = (ci >> 3) & 3, j = ci & 7;
#pragma unroll
    for (int kgt = 0; kgt < 9; ++kgt) {
        float v = w[(size_t)t * 9 + kgt];
        wt[((((size_t)kgt * (CIN >> 5) + cci) * 4 + lg) * 64 + cout) * 8 + j] = (bf16)v;
    }
}

// gc_w fp32 [128][128] -> wt[(((ks*4+lg)*128)+cout)*8+j]
__global__ __launch_bounds__(256) void prep_1x1_w(const float* __restrict__ w,
                                                  bf16* __restrict__ wt)
{
    int t = blockIdx.x * 256 + threadIdx.x;      // cout*128+ci, 16384
    int cout = t >> 7, ci = t & 127;
    int ks = ci >> 5, lg = (ci >> 3) & 3, j = ci & 7;
    wt[(((size_t)(ks * 4 + lg) * 128) + cout) * 8 + j] = (bf16)w[t];
}

// ---------------------------------------------------------------------------
// x fp32 NCHW [16][64][128][128] -> bf16 NHWC [16][128][128][64]
// ---------------------------------------------------------------------------
__global__ __launch_bounds__(256) void cvt_x_nhwc(const float* __restrict__ x,
                                                  bf16* __restrict__ xb)
{
    __shared__ float t_lds[64 * 68];
    const int bx = blockIdx.x;          // y = bx>>1, half = bx&1
    const int b  = blockIdx.y;
    const int y  = bx >> 1, x0 = (bx & 1) * 64;
    const int tid = threadIdx.x;

    for (int f = tid; f < 64 * 16; f += 256) {
        int c = f >> 4, xu = f & 15;
        float4 v = *(const float4*)&x[((size_t)(b * 64 + c) << 14) + (y << 7) + x0 + xu * 4];
        t_lds[(xu * 4 + 0) * 68 + c] = v.x;
        t_lds[(xu * 4 + 1) * 68 + c] = v.y;
        t_lds[(xu * 4 + 2) * 68 + c] = v.z;
        t_lds[(xu * 4 + 3) * 68 + c] = v.w;
    }
    __syncthreads();
    for (int f = tid; f < 64 * 8; f += 256) {
        int xx = f >> 3, cu = f & 7;
        const float* p = &t_lds[xx * 68 + cu * 8];
        bf16x8 v;
#pragma unroll
        for (int j = 0; j < 8; ++j) v[j] = (bf16)p[j];
        *(bf16x8*)&xb[((size_t)((b * 128 + y) * 128) + x0 + xx) * 64 + cu * 8] = v;
    }
}

// ---------------------------------------------------------------------------
// conv3x3 MFMA implicit GEMM v2. 8 waves, y-tile 8 x x-tile 64.
// A-fragments loaded directly from fragment-major bf16 weights (L2).
// Input halo [10][66][40] bf16 in LDS. 2 barriers per ci-chunk.
// ---------------------------------------------------------------------------
template<int CIN, int OUTMODE>
__global__ __launch_bounds__(512) void conv3x3_mfma(
    const bf16* __restrict__ in, const bf16* __restrict__ wt,
    const float* __restrict__ bias,
    const float* __restrict__ bg, const float* __restrict__ bb,
    const float* __restrict__ bm, const float* __restrict__ bv,
    const float* __restrict__ resid, void* __restrict__ outp)
{
    __shared__ bf16 in_lds[10 * 66 * 40];     // 52,800 B
    const int tile = blockIdx.x;              // 0..31
    const int b    = blockIdx.y;
    const int x0 = (tile & 1) * 64;
    const int y0 = (tile >> 1) * 8;
    const int tid  = threadIdx.x;
    const int wid  = tid >> 6;
    const int lane = tid & 63;
    const int lix  = lane & 15, lg = lane >> 4;

    f32x4 acc[4][4];
#pragma unroll
    for (int i = 0; i < 4; ++i)
#pragma unroll
        for (int j = 0; j < 4; ++j) acc[i][j] = zero4();

    for (int cci = 0; cci < (CIN >> 5); ++cci) {
        __syncthreads();
        for (int f = tid; f < 10 * 66 * 4; f += 512) {
            int u = f & 3, pix = f >> 2;
            int iy = pix / 66, ix = pix - iy * 66;
            int gy = y0 + iy - 1, gx = x0 + ix - 1;
            bf16x8 v = zero8();
            if ((unsigned)gy < 128u && (unsigned)gx < 128u)
                v = *(const bf16x8*)&in[((size_t)((b * 128 + gy) * 128 + gx)) * CIN + cci * 32 + u * 8];
            *(bf16x8*)&in_lds[(iy * 66 + ix) * 40 + u * 8] = v;
        }
        __syncthreads();
#pragma unroll
        for (int kg = 0; kg < 3; ++kg) {
#pragma unroll
            for (int t = 0; t < 3; ++t) {
                const int kgt = kg * 3 + t;
                const bf16* wp = wt + ((((size_t)kgt * (CIN >> 5) + cci) * 4 + lg) * 64) * 8;
                bf16x8 af[4];
#pragma unroll
                for (int mi = 0; mi < 4; ++mi)
                    af[mi] = *(const bf16x8*)&wp[(mi * 16 + lix) * 8];
                const int rowb = (wid + kg) * 66 + lix + t;
#pragma unroll
                for (int nj = 0; nj < 4; ++nj) {
                    bf16x8 bfr = *(const bf16x8*)&in_lds[(rowb + nj * 16) * 40 + lg * 8];
#pragma unroll
                    for (int mi = 0; mi < 4; ++mi)
                        acc[mi][nj] = mfma16(af[mi], bfr, acc[mi][nj]);
                }
            }
        }
    }

    const int gy = y0 + wid;
#pragma unroll
    for (int mi = 0; mi < 4; ++mi) {
        float A[4], Bc[4];
#pragma unroll
        for (int r = 0; r < 4; ++r) {
            int c = mi * 16 + lg * 4 + r;
            float s = bg[c] * rsqrtf(bv[c] + EPSV);
            A[r]  = s;
            Bc[r] = bias[c] * s + bb[c] - bm[c] * s;
        }
        if (OUTMODE == 0) {
            bf16* out = (bf16*)outp;
#pragma unroll
            for (int nj = 0; nj < 4; ++nj) {
                int px = x0 + nj * 16 + lix;
                bf16x4 vv;
#pragma unroll
                for (int r = 0; r < 4; ++r)
                    vv[r] = (bf16)(acc[mi][nj][r] * A[r] + Bc[r]);
                *(bf16x4*)&out[((size_t)((b * 128 + gy) * 128) + px) * 64 + mi * 16 + lg * 4] = vv;
            }
        } else {
            float* out = (float*)outp;
#pragma unroll
            for (int nj = 0; nj < 4; ++nj) {
                int px = x0 + nj * 16 + lix;
#pragma unroll
                for (int r = 0; r < 4; ++r) {
                    int c = mi * 16 + lg * 4 + r;
                    size_t oi = ((size_t)(b * 64 + c) << 14) + (gy << 7) + px;
                    out[oi] = acc[mi][nj][r] * A[r] + Bc[r] + resid[oi];
                }
            }
        }
    }
}

// ---------------------------------------------------------------------------
// q[b][n][c] = h[b][4*(n/32)][4*(n%32)][c]
// ---------------------------------------------------------------------------
__global__ __launch_bounds__(256) void gather_q(const bf16* __restrict__ h,
                                                bf16* __restrict__ q)
{
    int t = blockIdx.x * 256 + threadIdx.x;   // < 16*1024*8
    int cu = t & 7, n = (t >> 3) & 1023, b = t >> 13;
    int y = (n >> 5) << 2, x = (n & 31) << 2;
    bf16x8 v = *(const bf16x8*)&h[((size_t)((b * 128 + y) * 128 + x)) * 64 + cu * 8];
    *(bf16x8*)&q[((size_t)(b * 1024 + n)) * 64 + cu * 8] = v;
}

// ---------------------------------------------------------------------------
// Fused flash attention: per block 64 q-rows (4 waves x 16), loop m-tiles of
// 128. S^T = mfma(K,Q) so softmax column n is lane-local (col=lix); online
// max/sum reduced over lg via shfl_xor(16/32). P via per-wave LDS tile.
// o[b][n][c] bf16 out.
// ---------------------------------------------------------------------------
__global__ __launch_bounds__(256) void attn_fused(const bf16* __restrict__ q,
                                                  bf16* __restrict__ o)
{
    __shared__ bf16 qn[64 * 72];               //  9,216 B
    __shared__ bf16 kn[128 * 72];              // 18,432 B
    __shared__ bf16 vt[64 * 136];              // 17,408 B
    __shared__ bf16 pl[4][16 * 136];           // 17,408 B
    __shared__ __align__(16) float fac[4][16]; //    256 B
    const int n0 = blockIdx.x * 64, b = blockIdx.y;
    const int tid = threadIdx.x, w = tid >> 6, lane = tid & 63;
    const int lix = lane & 15, lg = lane >> 4;
    const bf16* qb = q + ((size_t)b << 16);

    for (int f = tid; f < 512; f += 256) {
        int row = f >> 3, cu = f & 7;
        *(bf16x8*)&qn[row * 72 + cu * 8] =
            *(const bf16x8*)&qb[(size_t)(n0 + row) * 64 + cu * 8];
    }

    float m_run = -3.0e38f, l_run = 0.f;
    f32x4 oacc[4];
#pragma unroll
    for (int ct = 0; ct < 4; ++ct) oacc[ct] = zero4();

    for (int mt = 0; mt < 1024; mt += 128) {
        __syncthreads();
        for (int f = tid; f < 1024; f += 256) {
            int row = f >> 3, cu = f & 7;
            *(bf16x8*)&kn[row * 72 + cu * 8] =
                *(const bf16x8*)&qb[(size_t)(mt + row) * 64 + cu * 8];
        }
        for (int f = tid; f < 512; f += 256) {
            int mp = f >> 3, cu = f & 7;
            int m = mp * 2;
            bf16x8 a = *(const bf16x8*)&qb[(size_t)(mt + m) * 64 + cu * 8];
            bf16x8 c = *(const bf16x8*)&qb[(size_t)(mt + m + 1) * 64 + cu * 8];
#pragma unroll
            for (int j = 0; j < 8; ++j) {
                bf16x2 pr = {a[j], c[j]};
                *(bf16x2*)&vt[(cu * 8 + j) * 136 + m] = pr;
            }
        }
        __syncthreads();

        bf16x8 bq0 = *(const bf16x8*)&qn[(w * 16 + lix) * 72 + lg * 8];
        bf16x8 bq1 = *(const bf16x8*)&qn[(w * 16 + lix) * 72 + 32 + lg * 8];

        f32x4 s[8];
#pragma unroll
        for (int t = 0; t < 8; ++t) {
            bf16x8 a0 = *(const bf16x8*)&kn[(t * 16 + lix) * 72 + lg * 8];
            bf16x8 a1 = *(const bf16x8*)&kn[(t * 16 + lix) * 72 + 32 + lg * 8];
            s[t] = mfma16(a0, bq0, zero4());
            s[t] = mfma16(a1, bq1, s[t]);
        }

        float mx = -3.0e38f;
#pragma unroll
        for (int t = 0; t < 8; ++t)
#pragma unroll
            for (int r = 0; r < 4; ++r) { s[t][r] *= 0.125f; mx = fmaxf(mx, s[t][r]); }
        mx = fmaxf(mx, __shfl_xor(mx, 16));
        mx = fmaxf(mx, __shfl_xor(mx, 32));
        float m_new = fmaxf(m_run, mx);
        float alpha = __expf(m_run - m_new);

        float psum = 0.f;
#pragma unroll
        for (int t = 0; t < 8; ++t) {
            float p0 = __expf(s[t][0] - m_new), p1 = __expf(s[t][1] - m_new);
            float p2 = __expf(s[t][2] - m_new), p3 = __expf(s[t][3] - m_new);
            psum += (p0 + p1) + (p2 + p3);
            bf16x2 v01 = {(bf16)p0, (bf16)p1};
            bf16x2 v23 = {(bf16)p2, (bf16)p3};
            *(bf16x2*)&pl[w][lix * 136 + t * 16 + lg * 4]     = v01;
            *(bf16x2*)&pl[w][lix * 136 + t * 16 + lg * 4 + 2] = v23;
        }
        psum += __shfl_xor(psum, 16);
        psum += __shfl_xor(psum, 32);
        l_run = l_run * alpha + psum;
        m_run = m_new;
        if (lg == 0) fac[w][lix] = alpha;

        float4 a4 = *(const float4*)&fac[w][lg * 4];
        float aa[4] = {a4.x, a4.y, a4.z, a4.w};
#pragma unroll
        for (int ct = 0; ct < 4; ++ct)
#pragma unroll
            for (int r = 0; r < 4; ++r) oacc[ct][r] *= aa[r];

#pragma unroll
        for (int kk = 0; kk < 4; ++kk) {
            bf16x8 pa = *(const bf16x8*)&pl[w][lix * 136 + kk * 32 + lg * 8];
#pragma unroll
            for (int ct = 0; ct < 4; ++ct) {
                bf16x8 bv = *(const bf16x8*)&vt[(ct * 16 + lix) * 136 + kk * 32 + lg * 8];
                oacc[ct] = mfma16(pa, bv, oacc[ct]);
            }
        }
    }

    if (lg == 0) fac[w][lix] = l_run;
    float4 l4 = *(const float4*)&fac[w][lg * 4];
    float ll[4] = {1.f / l4.x, 1.f / l4.y, 1.f / l4.z, 1.f / l4.w};
#pragma unroll
    for (int ct = 0; ct < 4; ++ct)
#pragma unroll
        for (int r = 0; r < 4; ++r) {
            int n = n0 + w * 16 + lg * 4 + r;
            int c = ct * 16 + lix;
            o[((size_t)(b * 1024 + n)) * 64 + c] = (bf16)(oacc[ct][r] * ll[r]);
        }
}

// ---------------------------------------------------------------------------
// conv1x1 (128->128) + BN + GELU. Weights direct from fragment-major bf16.
// ---------------------------------------------------------------------------
__global__ __launch_bounds__(256) void conv1x1_mfma(
    const bf16* __restrict__ h, const bf16* __restrict__ ov,
    const bf16* __restrict__ wt, const float* __restrict__ bias,
    const float* __restrict__ bg, const float* __restrict__ bb,
    const float* __restrict__ bm, const float* __restrict__ bv,
    bf16* __restrict__ g)
{
    __shared__ bf16 in1[128 * 136];           // 34,816 B
    const int y = blockIdx.x, b = blockIdx.y;
    const int tid = threadIdx.x;
    const int wid = tid >> 6, lane = tid & 63;
    const int lix = lane & 15, lg = lane >> 4;
    const int wm = wid >> 1, wn = wid & 1;

    for (int f = tid; f < 128 * 16; f += 256) {
        int px = f >> 4, cu = f & 15;
        bf16x8 v;
        if (cu < 8) {
            v = *(const bf16x8*)&h[((size_t)((b * 128 + y) * 128 + px)) * 64 + cu * 8];
        } else {
            int n = ((y >> 2) << 5) + (px >> 2);
            v = *(const bf16x8*)&ov[((size_t)(b * 1024 + n)) * 64 + (cu - 8) * 8];
        }
        *(bf16x8*)&in1[px * 136 + cu * 8] = v;
    }
    __syncthreads();

    f32x4 acc[4][4];
#pragma unroll
    for (int i = 0; i < 4; ++i)
#pragma unroll
        for (int j = 0; j < 4; ++j) acc[i][j] = zero4();

#pragma unroll
    for (int ks = 0; ks < 4; ++ks) {
        bf16x8 af[4], bfv[4];
#pragma unroll
        for (int mi = 0; mi < 4; ++mi)
            af[mi] = *(const bf16x8*)&wt[(((size_t)(ks * 4 + lg) * 128) + wm * 64 + mi * 16 + lix) * 8];
#pragma unroll
        for (int nj = 0; nj < 4; ++nj)
            bfv[nj] = *(const bf16x8*)&in1[(wn * 64 + nj * 16 + lix) * 136 + ks * 32 + lg * 8];
#pragma unroll
        for (int mi = 0; mi < 4; ++mi)
#pragma unroll
            for (int nj = 0; nj < 4; ++nj)
                acc[mi][nj] = mfma16(af[mi], bfv[nj], acc[mi][nj]);
    }

#pragma unroll
    for (int mi = 0; mi < 4; ++mi) {
        float A[4], Bc[4];
#pragma unroll
        for (int r = 0; r < 4; ++r) {
            int c = wm * 64 + mi * 16 + lg * 4 + r;
            float s = bg[c] * rsqrtf(bv[c] + EPSV);
            A[r]  = s;
            Bc[r] = bias[c] * s + bb[c] - bm[c] * s;
        }
#pragma unroll
        for (int nj = 0; nj < 4; ++nj) {
            int px = wn * 64 + nj * 16 + lix;
            bf16x4 vv;
#pragma unroll
            for (int r = 0; r < 4; ++r) {
                float val = acc[mi][nj][r] * A[r] + Bc[r];
                float ge  = 0.5f * val * (1.f + erff(val * 0.70710678f));
                vv[r] = (bf16)ge;
            }
            *(bf16x4*)&g[((size_t)((b * 128 + y) * 128 + px)) * 128 + wm * 64 + mi * 16 + lg * 4] = vv;
        }
    }
}

// ---------------------------------------------------------------------------
extern "C" void kernel_launch(void* const* d_in, const int* in_sizes, int n_in,
                              void* d_out, int out_size, void* d_ws, size_t ws_size,
                              hipStream_t stream)
{
    const float* x     = (const float*)d_in[0];
    const float* fc1_w = (const float*)d_in[1];
    const float* fc1_b = (const float*)d_in[2];
    const float* bn1_g = (const float*)d_in[3];
    const float* bn1_b = (const float*)d_in[4];
    const float* bn1_m = (const float*)d_in[5];
    const float* bn1_v = (const float*)d_in[6];
    const float* gc_w  = (const float*)d_in[7];
    const float* gc_b  = (const float*)d_in[8];
    const float* bng_g = (const float*)d_in[9];
    const float* bng_b = (const float*)d_in[10];
    const float* bng_m = (const float*)d_in[11];
    const float* bng_v = (const float*)d_in[12];
    const float* fc2_w = (const float*)d_in[13];
    const float* fc2_b = (const float*)d_in[14];
    const float* bn2_g = (const float*)d_in[15];
    const float* bn2_b = (const float*)d_in[16];
    const float* bn2_m = (const float*)d_in[17];
    const float* bn2_v = (const float*)d_in[18];

    char* wsb = (char*)d_ws;
    bf16* x_bf = (bf16*)wsb;                      // 33,554,432 B
    bf16* h    = (bf16*)(wsb + 33554432);         // 33,554,432 B
    bf16* g    = (bf16*)(wsb + 67108864);         // 67,108,864 B
    bf16* q    = (bf16*)(wsb + 134217728);        //  2,097,152 B
    bf16* o    = (bf16*)(wsb + 136314880);        //  2,097,152 B
    bf16* wt1  = (bf16*)(wsb + 138412032);        //     73,728 B
    bf16* wt2  = (bf16*)(wsb + 138485760);        //    147,456 B
    bf16* wtg  = (bf16*)(wsb + 138633216);        //     32,768 B

    prep_conv_w<64><<<16, 256, 0, stream>>>(fc1_w, wt1);
    prep_conv_w<128><<<32, 256, 0, stream>>>(fc2_w, wt2);
    prep_1x1_w<<<64, 256, 0, stream>>>(gc_w, wtg);

    cvt_x_nhwc<<<dim3(256, 16), 256, 0, stream>>>(x, x_bf);

    conv3x3_mfma<64, 0><<<dim3(32, 16), 512, 0, stream>>>(
        x_bf, wt1, fc1_b, bn1_g, bn1_b, bn1_m, bn1_v, nullptr, h);

    gather_q<<<512, 256, 0, stream>>>(h, q);

    attn_fused<<<dim3(16, 16), 256, 0, stream>>>(q, o);

    conv1x1_mfma<<<dim3(128, 16), 256, 0, stream>>>(
        h, o, wtg, gc_b, bng_g, bng_b, bng_m, bng_v, g);

    conv3x3_mfma<128, 1><<<dim3(32, 16), 512, 0, stream>>>(
        g, wt2, fc2_b, bn2_g, bn2_b, bn2_m, bn2_v, x, (float*)d_out);
}

// Round 4
// 197.609 us; speedup vs baseline: 10.4788x; 1.0492x over previous
//
#include <hip/hip_runtime.h>
#include <math.h>

#define EPSV 1e-5f

typedef __bf16 bf16;
using bf16x8 = __attribute__((ext_vector_type(8))) __bf16;
using bf16x4 = __attribute__((ext_vector_type(4))) __bf16;
using bf16x2 = __attribute__((ext_vector_type(2))) __bf16;
using f32x4  = __attribute__((ext_vector_type(4))) float;

static __device__ __forceinline__ f32x4 mfma16(bf16x8 a, bf16x8 b, f32x4 c) {
    return __builtin_amdgcn_mfma_f32_16x16x32_bf16(a, b, c, 0, 0, 0);
}
static __device__ __forceinline__ f32x4 zero4() {
    f32x4 z = {0.f, 0.f, 0.f, 0.f};
    return z;
}
static __device__ __forceinline__ bf16x8 zero8() {
    bf16x8 z = {(bf16)0.f,(bf16)0.f,(bf16)0.f,(bf16)0.f,
                (bf16)0.f,(bf16)0.f,(bf16)0.f,(bf16)0.f};
    return z;
}

// exact-GELU via Abramowitz-Stegun 7.1.26 erf (|err| <= 1.5e-7)
static __device__ __forceinline__ float gelu_f(float v) {
    float z = fabsf(v) * 0.70710678118f;
    float t = __builtin_amdgcn_rcpf(1.f + 0.3275911f * z);
    float poly = t * (0.254829592f + t * (-0.284496736f + t * (1.421413741f +
                 t * (-1.453152027f + t * 1.061405429f))));
    float e = __expf(-z * z);
    float erfv = copysignf(1.f - poly * e, v);
    return 0.5f * v * (1.f + erfv);
}

// ---------------------------------------------------------------------------
// Weight prep: conv3x3 fp32 [cout][CIN][3][3] -> bf16 fragment-major
// wt[(((kgt*(CIN/32)+cci)*4+lg)*64 + cout)*8 + j], ci = cci*32+lg*8+j.
// ---------------------------------------------------------------------------
template<int CIN>
__global__ __launch_bounds__(256) void prep_conv_w(const float* __restrict__ w,
                                                   bf16* __restrict__ wt)
{
    int t = blockIdx.x * 256 + threadIdx.x;      // cout*CIN + ci
    if (t >= 64 * CIN) return;
    int cout = t / CIN, ci = t - cout * CIN;
    int cci = ci >> 5, lg = (ci >> 3) & 3, j = ci & 7;
#pragma unroll
    for (int kgt = 0; kgt < 9; ++kgt) {
        float v = w[(size_t)t * 9 + kgt];
        wt[((((size_t)kgt * (CIN >> 5) + cci) * 4 + lg) * 64 + cout) * 8 + j] = (bf16)v;
    }
}

// gc_w fp32 [128][128] -> wt[(((ks*4+lg)*128)+cout)*8+j]
__global__ __launch_bounds__(256) void prep_1x1_w(const float* __restrict__ w,
                                                  bf16* __restrict__ wt)
{
    int t = blockIdx.x * 256 + threadIdx.x;      // cout*128+ci, 16384
    int cout = t >> 7, ci = t & 127;
    int ks = ci >> 5, lg = (ci >> 3) & 3, j = ci & 7;
    wt[(((size_t)(ks * 4 + lg) * 128) + cout) * 8 + j] = (bf16)w[t];
}

// ---------------------------------------------------------------------------
// x fp32 NCHW [16][64][128][128] -> bf16 NHWC [16][128][128][64]
// ---------------------------------------------------------------------------
__global__ __launch_bounds__(256) void cvt_x_nhwc(const float* __restrict__ x,
                                                  bf16* __restrict__ xb)
{
    __shared__ float t_lds[64 * 68];
    const int bx = blockIdx.x;          // y = bx>>1, half = bx&1
    const int b  = blockIdx.y;
    const int y  = bx >> 1, x0 = (bx & 1) * 64;
    const int tid = threadIdx.x;

    for (int f = tid; f < 64 * 16; f += 256) {
        int c = f >> 4, xu = f & 15;
        float4 v = *(const float4*)&x[((size_t)(b * 64 + c) << 14) + (y << 7) + x0 + xu * 4];
        t_lds[(xu * 4 + 0) * 68 + c] = v.x;
        t_lds[(xu * 4 + 1) * 68 + c] = v.y;
        t_lds[(xu * 4 + 2) * 68 + c] = v.z;
        t_lds[(xu * 4 + 3) * 68 + c] = v.w;
    }
    __syncthreads();
    for (int f = tid; f < 64 * 8; f += 256) {
        int xx = f >> 3, cu = f & 7;
        const float* p = &t_lds[xx * 68 + cu * 8];
        bf16x8 v;
#pragma unroll
        for (int j = 0; j < 8; ++j) v[j] = (bf16)p[j];
        *(bf16x8*)&xb[((size_t)((b * 128 + y) * 128) + x0 + xx) * 64 + cu * 8] = v;
    }
}

// ---------------------------------------------------------------------------
// conv3x3 MFMA implicit GEMM v3: x-tile 32, y-tile 8, 8 waves.
// Register double-buffered input staging (T14: load chunk k+1 while
// computing chunk k); weight fragments double-buffered one kgt ahead.
// OUTMODE 0: bf16 NHWC + BN via coalesced LDS-transposed store.
// OUTMODE 1: fp32 NCHW + BN + residual direct.
// ---------------------------------------------------------------------------
template<int CIN, int OUTMODE>
__global__ __launch_bounds__(512, 4) void conv3x3_mfma(
    const bf16* __restrict__ in, const bf16* __restrict__ wt,
    const float* __restrict__ bias,
    const float* __restrict__ bg, const float* __restrict__ bb,
    const float* __restrict__ bm, const float* __restrict__ bv,
    const float* __restrict__ resid, void* __restrict__ outp)
{
    constexpr int NC = CIN >> 5;
    __shared__ bf16 in_lds[10 * 34 * 40];     // 27,200 B (reused as out-stage)

    const int tile = blockIdx.x;              // 0..63
    const int b    = blockIdx.y;
    const int x0 = (tile & 3) * 32;
    const int y0 = (tile >> 2) * 8;
    const int tid  = threadIdx.x;
    const int wid  = tid >> 6;
    const int lane = tid & 63;
    const int lix  = lane & 15, lg = lane >> 4;

    f32x4 acc[4][2];
#pragma unroll
    for (int i = 0; i < 4; ++i)
#pragma unroll
        for (int j = 0; j < 2; ++j) acc[i][j] = zero4();

    // ---- staging helpers (1360 16B-units: 2 full rounds + tail tid<336) ----
    auto load_chunk = [&](int cci, bf16x8* pre) {
#pragma unroll
        for (int k = 0; k < 2; ++k) {
            int f = tid + k * 512;
            int u = f & 3, pix = f >> 2;
            int iy = pix / 34, ix = pix - iy * 34;
            int gy = y0 + iy - 1, gx = x0 + ix - 1;
            bf16x8 v = zero8();
            if ((unsigned)gy < 128u && (unsigned)gx < 128u)
                v = *(const bf16x8*)&in[((size_t)((b * 128 + gy) * 128 + gx)) * CIN + cci * 32 + u * 8];
            pre[k] = v;
        }
        {
            int f = 1024 + tid;
            int u = f & 3, pix = f >> 2;
            int iy = pix / 34, ix = pix - iy * 34;
            int gy = y0 + iy - 1, gx = x0 + ix - 1;
            bf16x8 v = zero8();
            if (tid < 336 && (unsigned)gy < 128u && (unsigned)gx < 128u)
                v = *(const bf16x8*)&in[((size_t)((b * 128 + gy) * 128 + gx)) * CIN + cci * 32 + u * 8];
            pre[2] = v;
        }
    };
    auto write_chunk = [&](const bf16x8* pre) {
#pragma unroll
        for (int k = 0; k < 2; ++k) {
            int f = tid + k * 512;
            int u = f & 3, pix = f >> 2;
            *(bf16x8*)&in_lds[pix * 40 + u * 8] = pre[k];
        }
        if (tid < 336) {
            int f = 1024 + tid;
            int u = f & 3, pix = f >> 2;
            *(bf16x8*)&in_lds[pix * 40 + u * 8] = pre[2];
        }
    };
    auto load_af = [&](int kgt, int cci, bf16x8* af) {
#pragma unroll
        for (int mi = 0; mi < 4; ++mi)
            af[mi] = *(const bf16x8*)&wt[((((size_t)kgt * NC + cci) * 4 + lg) * 64 + mi * 16 + lix) * 8];
    };
    auto compute = [&](int cci) {
        bf16x8 afA[4], afB[4];
        load_af(0, cci, afA);
#pragma unroll
        for (int kgt = 0; kgt < 9; ++kgt) {
            const int kg = kgt / 3, t = kgt % 3;
            bf16x8* cur = (kgt & 1) ? afB : afA;
            bf16x8* nxt = (kgt & 1) ? afA : afB;
            if (kgt < 8) load_af(kgt + 1, cci, nxt);
#pragma unroll
            for (int nj = 0; nj < 2; ++nj) {
                bf16x8 bfr = *(const bf16x8*)&in_lds[((wid + kg) * 34 + lix + t + nj * 16) * 40 + lg * 8];
#pragma unroll
                for (int mi = 0; mi < 4; ++mi)
                    acc[mi][nj] = mfma16(cur[mi], bfr, acc[mi][nj]);
            }
        }
    };

    bf16x8 preA[3], preB[3];
    load_chunk(0, preA);
#pragma unroll 1
    for (int cci = 0; cci < NC; cci += 2) {
        __syncthreads();
        write_chunk(preA);
        if (cci + 1 < NC) load_chunk(cci + 1, preB);
        __syncthreads();
        compute(cci);
        __syncthreads();
        write_chunk(preB);
        if (cci + 2 < NC) load_chunk(cci + 2, preA);
        __syncthreads();
        compute(cci + 1);
    }

    if (OUTMODE == 0) {
        // coalesced store via LDS transpose: two gy-half passes of 4 rows
        bf16* out  = (bf16*)outp;
        bf16* stg  = in_lds;                 // [4*32][68] view, 17,408 B
#pragma unroll 1
        for (int p = 0; p < 2; ++p) {
            __syncthreads();
            if ((wid >> 2) == p) {
                int gyloc = wid & 3;
#pragma unroll
                for (int mi = 0; mi < 4; ++mi) {
                    float A[4], Bc[4];
#pragma unroll
                    for (int r = 0; r < 4; ++r) {
                        int c = mi * 16 + lg * 4 + r;
                        float s = bg[c] * rsqrtf(bv[c] + EPSV);
                        A[r]  = s;
                        Bc[r] = bias[c] * s + bb[c] - bm[c] * s;
                    }
#pragma unroll
                    for (int nj = 0; nj < 2; ++nj) {
                        int px = nj * 16 + lix;
                        bf16x4 vv;
#pragma unroll
                        for (int r = 0; r < 4; ++r)
                            vv[r] = (bf16)(acc[mi][nj][r] * A[r] + Bc[r]);
                        *(bf16x4*)&stg[(gyloc * 32 + px) * 68 + mi * 16 + lg * 4] = vv;
                    }
                }
            }
            __syncthreads();
#pragma unroll
            for (int k = 0; k < 2; ++k) {
                int idx = k * 512 + tid;          // 1024 16B-units
                int gyloc = idx >> 8, rem = idx & 255;
                int px = rem >> 3, cu = rem & 7;
                int gy = y0 + p * 4 + gyloc;
                bf16x8 v = *(const bf16x8*)&stg[(gyloc * 32 + px) * 68 + cu * 8];
                *(bf16x8*)&out[((size_t)((b * 128 + gy) * 128) + x0 + px) * 64 + cu * 8] = v;
            }
        }
    } else {
        float* out = (float*)outp;
        const int gy = y0 + wid;
#pragma unroll
        for (int mi = 0; mi < 4; ++mi) {
            float A[4], Bc[4];
#pragma unroll
            for (int r = 0; r < 4; ++r) {
                int c = mi * 16 + lg * 4 + r;
                float s = bg[c] * rsqrtf(bv[c] + EPSV);
                A[r]  = s;
                Bc[r] = bias[c] * s + bb[c] - bm[c] * s;
            }
#pragma unroll
            for (int nj = 0; nj < 2; ++nj) {
                int px = x0 + nj * 16 + lix;
#pragma unroll
                for (int r = 0; r < 4; ++r) {
                    int c = mi * 16 + lg * 4 + r;
                    size_t oi = ((size_t)(b * 64 + c) << 14) + (gy << 7) + px;
                    out[oi] = acc[mi][nj][r] * A[r] + Bc[r] + resid[oi];
                }
            }
        }
    }
}

// ---------------------------------------------------------------------------
// q[b][n][c] = h[b][4*(n/32)][4*(n%32)][c]
// ---------------------------------------------------------------------------
__global__ __launch_bounds__(256) void gather_q(const bf16* __restrict__ h,
                                                bf16* __restrict__ q)
{
    int t = blockIdx.x * 256 + threadIdx.x;   // < 16*1024*8
    int cu = t & 7, n = (t >> 3) & 1023, b = t >> 13;
    int y = (n >> 5) << 2, x = (n & 31) << 2;
    bf16x8 v = *(const bf16x8*)&h[((size_t)((b * 128 + y) * 128 + x)) * 64 + cu * 8];
    *(bf16x8*)&q[((size_t)(b * 1024 + n)) * 64 + cu * 8] = v;
}

// ---------------------------------------------------------------------------
// Fused flash attention (unchanged from r3).
// ---------------------------------------------------------------------------
__global__ __launch_bounds__(256) void attn_fused(const bf16* __restrict__ q,
                                                  bf16* __restrict__ o)
{
    __shared__ bf16 qn[64 * 72];
    __shared__ bf16 kn[128 * 72];
    __shared__ bf16 vt[64 * 136];
    __shared__ bf16 pl[4][16 * 136];
    __shared__ __align__(16) float fac[4][16];
    const int n0 = blockIdx.x * 64, b = blockIdx.y;
    const int tid = threadIdx.x, w = tid >> 6, lane = tid & 63;
    const int lix = lane & 15, lg = lane >> 4;
    const bf16* qb = q + ((size_t)b << 16);

    for (int f = tid; f < 512; f += 256) {
        int row = f >> 3, cu = f & 7;
        *(bf16x8*)&qn[row * 72 + cu * 8] =
            *(const bf16x8*)&qb[(size_t)(n0 + row) * 64 + cu * 8];
    }

    float m_run = -3.0e38f, l_run = 0.f;
    f32x4 oacc[4];
#pragma unroll
    for (int ct = 0; ct < 4; ++ct) oacc[ct] = zero4();

    for (int mt = 0; mt < 1024; mt += 128) {
        __syncthreads();
        for (int f = tid; f < 1024; f += 256) {
            int row = f >> 3, cu = f & 7;
            *(bf16x8*)&kn[row * 72 + cu * 8] =
                *(const bf16x8*)&qb[(size_t)(mt + row) * 64 + cu * 8];
        }
        for (int f = tid; f < 512; f += 256) {
            int mp = f >> 3, cu = f & 7;
            int m = mp * 2;
            bf16x8 a = *(const bf16x8*)&qb[(size_t)(mt + m) * 64 + cu * 8];
            bf16x8 c = *(const bf16x8*)&qb[(size_t)(mt + m + 1) * 64 + cu * 8];
#pragma unroll
            for (int j = 0; j < 8; ++j) {
                bf16x2 pr = {a[j], c[j]};
                *(bf16x2*)&vt[(cu * 8 + j) * 136 + m] = pr;
            }
        }
        __syncthreads();

        bf16x8 bq0 = *(const bf16x8*)&qn[(w * 16 + lix) * 72 + lg * 8];
        bf16x8 bq1 = *(const bf16x8*)&qn[(w * 16 + lix) * 72 + 32 + lg * 8];

        f32x4 s[8];
#pragma unroll
        for (int t = 0; t < 8; ++t) {
            bf16x8 a0 = *(const bf16x8*)&kn[(t * 16 + lix) * 72 + lg * 8];
            bf16x8 a1 = *(const bf16x8*)&kn[(t * 16 + lix) * 72 + 32 + lg * 8];
            s[t] = mfma16(a0, bq0, zero4());
            s[t] = mfma16(a1, bq1, s[t]);
        }

        float mx = -3.0e38f;
#pragma unroll
        for (int t = 0; t < 8; ++t)
#pragma unroll
            for (int r = 0; r < 4; ++r) { s[t][r] *= 0.125f; mx = fmaxf(mx, s[t][r]); }
        mx = fmaxf(mx, __shfl_xor(mx, 16));
        mx = fmaxf(mx, __shfl_xor(mx, 32));
        float m_new = fmaxf(m_run, mx);
        float alpha = __expf(m_run - m_new);

        float psum = 0.f;
#pragma unroll
        for (int t = 0; t < 8; ++t) {
            float p0 = __expf(s[t][0] - m_new), p1 = __expf(s[t][1] - m_new);
            float p2 = __expf(s[t][2] - m_new), p3 = __expf(s[t][3] - m_new);
            psum += (p0 + p1) + (p2 + p3);
            bf16x2 v01 = {(bf16)p0, (bf16)p1};
            bf16x2 v23 = {(bf16)p2, (bf16)p3};
            *(bf16x2*)&pl[w][lix * 136 + t * 16 + lg * 4]     = v01;
            *(bf16x2*)&pl[w][lix * 136 + t * 16 + lg * 4 + 2] = v23;
        }
        psum += __shfl_xor(psum, 16);
        psum += __shfl_xor(psum, 32);
        l_run = l_run * alpha + psum;
        m_run = m_new;
        if (lg == 0) fac[w][lix] = alpha;

        float4 a4 = *(const float4*)&fac[w][lg * 4];
        float aa[4] = {a4.x, a4.y, a4.z, a4.w};
#pragma unroll
        for (int ct = 0; ct < 4; ++ct)
#pragma unroll
            for (int r = 0; r < 4; ++r) oacc[ct][r] *= aa[r];

#pragma unroll
        for (int kk = 0; kk < 4; ++kk) {
            bf16x8 pa = *(const bf16x8*)&pl[w][lix * 136 + kk * 32 + lg * 8];
#pragma unroll
            for (int ct = 0; ct < 4; ++ct) {
                bf16x8 bv = *(const bf16x8*)&vt[(ct * 16 + lix) * 136 + kk * 32 + lg * 8];
                oacc[ct] = mfma16(pa, bv, oacc[ct]);
            }
        }
    }

    if (lg == 0) fac[w][lix] = l_run;
    float4 l4 = *(const float4*)&fac[w][lg * 4];
    float ll[4] = {1.f / l4.x, 1.f / l4.y, 1.f / l4.z, 1.f / l4.w};
#pragma unroll
    for (int ct = 0; ct < 4; ++ct)
#pragma unroll
        for (int r = 0; r < 4; ++r) {
            int n = n0 + w * 16 + lg * 4 + r;
            int c = ct * 16 + lix;
            o[((size_t)(b * 1024 + n)) * 64 + c] = (bf16)(oacc[ct][r] * ll[r]);
        }
}

// ---------------------------------------------------------------------------
// conv1x1 (128->128) + BN + fast exact GELU; coalesced store via LDS.
// ---------------------------------------------------------------------------
__global__ __launch_bounds__(256) void conv1x1_mfma(
    const bf16* __restrict__ h, const bf16* __restrict__ ov,
    const bf16* __restrict__ wt, const float* __restrict__ bias,
    const float* __restrict__ bg, const float* __restrict__ bb,
    const float* __restrict__ bm, const float* __restrict__ bv,
    bf16* __restrict__ g)
{
    __shared__ bf16 in1[128 * 136];           // 34,816 B (reused as out-stage)
    const int y = blockIdx.x, b = blockIdx.y;
    const int tid = threadIdx.x;
    const int wid = tid >> 6, lane = tid & 63;
    const int lix = lane & 15, lg = lane >> 4;
    const int wm = wid >> 1, wn = wid & 1;

    for (int f = tid; f < 128 * 16; f += 256) {
        int px = f >> 4, cu = f & 15;
        bf16x8 v;
        if (cu < 8) {
            v = *(const bf16x8*)&h[((size_t)((b * 128 + y) * 128 + px)) * 64 + cu * 8];
        } else {
            int n = ((y >> 2) << 5) + (px >> 2);
            v = *(const bf16x8*)&ov[((size_t)(b * 1024 + n)) * 64 + (cu - 8) * 8];
        }
        *(bf16x8*)&in1[px * 136 + cu * 8] = v;
    }
    __syncthreads();

    f32x4 acc[4][4];
#pragma unroll
    for (int i = 0; i < 4; ++i)
#pragma unroll
        for (int j = 0; j < 4; ++j) acc[i][j] = zero4();

#pragma unroll
    for (int ks = 0; ks < 4; ++ks) {
        bf16x8 af[4], bfv[4];
#pragma unroll
        for (int mi = 0; mi < 4; ++mi)
            af[mi] = *(const bf16x8*)&wt[(((size_t)(ks * 4 + lg) * 128) + wm * 64 + mi * 16 + lix) * 8];
#pragma unroll
        for (int nj = 0; nj < 4; ++nj)
            bfv[nj] = *(const bf16x8*)&in1[(wn * 64 + nj * 16 + lix) * 136 + ks * 32 + lg * 8];
#pragma unroll
        for (int mi = 0; mi < 4; ++mi)
#pragma unroll
            for (int nj = 0; nj < 4; ++nj)
                acc[mi][nj] = mfma16(af[mi], bfv[nj], acc[mi][nj]);
    }

    __syncthreads();                           // done reading in1
    bf16* stg = in1;                           // [128 px][132] view
#pragma unroll
    for (int mi = 0; mi < 4; ++mi) {
        float A[4], Bc[4];
#pragma unroll
        for (int r = 0; r < 4; ++r) {
            int c = wm * 64 + mi * 16 + lg * 4 + r;
            float s = bg[c] * rsqrtf(bv[c] + EPSV);
            A[r]  = s;
            Bc[r] = bias[c] * s + bb[c] - bm[c] * s;
        }
#pragma unroll
        for (int nj = 0; nj < 4; ++nj) {
            int px = wn * 64 + nj * 16 + lix;
            bf16x4 vv;
#pragma unroll
            for (int r = 0; r < 4; ++r)
                vv[r] = (bf16)gelu_f(acc[mi][nj][r] * A[r] + Bc[r]);
            *(bf16x4*)&stg[px * 132 + wm * 64 + mi * 16 + lg * 4] = vv;
        }
    }
    __syncthreads();
#pragma unroll
    for (int k = 0; k < 8; ++k) {
        int idx = k * 256 + tid;               // 2048 16B-units
        int px = idx >> 4, cu = idx & 15;
        bf16x8 v = *(const bf16x8*)&stg[px * 132 + cu * 8];
        *(bf16x8*)&g[((size_t)((b * 128 + y) * 128) + px) * 128 + cu * 8] = v;
    }
}

// ---------------------------------------------------------------------------
extern "C" void kernel_launch(void* const* d_in, const int* in_sizes, int n_in,
                              void* d_out, int out_size, void* d_ws, size_t ws_size,
                              hipStream_t stream)
{
    const float* x     = (const float*)d_in[0];
    const float* fc1_w = (const float*)d_in[1];
    const float* fc1_b = (const float*)d_in[2];
    const float* bn1_g = (const float*)d_in[3];
    const float* bn1_b = (const float*)d_in[4];
    const float* bn1_m = (const float*)d_in[5];
    const float* bn1_v = (const float*)d_in[6];
    const float* gc_w  = (const float*)d_in[7];
    const float* gc_b  = (const float*)d_in[8];
    const float* bng_g = (const float*)d_in[9];
    const float* bng_b = (const float*)d_in[10];
    const float* bng_m = (const float*)d_in[11];
    const float* bng_v = (const float*)d_in[12];
    const float* fc2_w = (const float*)d_in[13];
    const float* fc2_b = (const float*)d_in[14];
    const float* bn2_g = (const float*)d_in[15];
    const float* bn2_b = (const float*)d_in[16];
    const float* bn2_m = (const float*)d_in[17];
    const float* bn2_v = (const float*)d_in[18];

    char* wsb = (char*)d_ws;
    bf16* x_bf = (bf16*)wsb;                      // 33,554,432 B
    bf16* h    = (bf16*)(wsb + 33554432);         // 33,554,432 B
    bf16* g    = (bf16*)(wsb + 67108864);         // 67,108,864 B
    bf16* q    = (bf16*)(wsb + 134217728);        //  2,097,152 B
    bf16* o    = (bf16*)(wsb + 136314880);        //  2,097,152 B
    bf16* wt1  = (bf16*)(wsb + 138412032);        //     73,728 B
    bf16* wt2  = (bf16*)(wsb + 138485760);        //    147,456 B
    bf16* wtg  = (bf16*)(wsb + 138633216);        //     32,768 B

    prep_conv_w<64><<<16, 256, 0, stream>>>(fc1_w, wt1);
    prep_conv_w<128><<<32, 256, 0, stream>>>(fc2_w, wt2);
    prep_1x1_w<<<64, 256, 0, stream>>>(gc_w, wtg);

    cvt_x_nhwc<<<dim3(256, 16), 256, 0, stream>>>(x, x_bf);

    conv3x3_mfma<64, 0><<<dim3(64, 16), 512, 0, stream>>>(
        x_bf, wt1, fc1_b, bn1_g, bn1_b, bn1_m, bn1_v, nullptr, h);

    gather_q<<<512, 256, 0, stream>>>(h, q);

    attn_fused<<<dim3(16, 16), 256, 0, stream>>>(q, o);

    conv1x1_mfma<<<dim3(128, 16), 256, 0, stream>>>(
        h, o, wtg, gc_b, bng_g, bng_b, bng_m, bng_v, g);

    conv3x3_mfma<128, 1><<<dim3(64, 16), 512, 0, stream>>>(
        g, wt2, fc2_b, bn2_g, bn2_b, bn2_m, bn2_v, x, (float*)d_out);
}